// Round 2
// baseline (505.638 us; speedup 1.0000x reference)
//
#include <hip/hip_runtime.h>
#include <hip/hip_bf16.h>

#define N_NODES 262144
#define C_CH 64
#define K_NBR 16
#define NCLS 40

typedef unsigned short ushort_t;

__device__ __forceinline__ float bu2f(ushort_t u) {
    union { unsigned u32; float f; } v; v.u32 = ((unsigned)u) << 16; return v.f;
}
__device__ __forceinline__ ushort_t f2bu(float f) {
    union { float f; unsigned u; } v; v.f = f;
    unsigned r = v.u + 0x7FFFu + ((v.u >> 16) & 1u);
    return (ushort_t)(r >> 16);
}

// dtype-dispatched scalar accessors
__device__ __forceinline__ float ldv(const ushort_t* p, long i) { return bu2f(p[i]); }
__device__ __forceinline__ float ldv(const float* p, long i)    { return p[i]; }
__device__ __forceinline__ void  stv(ushort_t* p, long i, float v) { p[i] = f2bu(v); }
__device__ __forceinline__ void  stv(float* p, long i, float v)    { p[i] = v; }
__device__ __forceinline__ int   ldi(const int* p, long i)       { return p[i]; }
__device__ __forceinline__ int   ldi(const long long* p, long i) { return (int)p[i]; }

// ---------------- Sniffer: decide x dtype (bf16 vs f32) and nbr dtype -------
// flags[0] = 1 if x is bf16 ; flags[1] = 1 if nbr is int64
__global__ void sniff_kernel(const void* __restrict__ x,
                             const void* __restrict__ nbr,
                             int* __restrict__ flags) {
    int lane = threadIdx.x;                 // 64 threads
    const ushort_t* xu = (const ushort_t*)x;
    ushort_t u = xu[lane];
    int e = (u >> 7) & 0xFF;                // bf16 exponent field
    bool ok = (u == 0) || (e >= 0x50 && e <= 0x90);   // N(0,1) bf16 range
    unsigned long long mb = __ballot(ok);
    const int* ni = (const int*)nbr;
    bool zodd = (ni[2 * lane + 1] == 0);    // int64 high words are all zero
    unsigned long long mz = __ballot(zodd);
    if (lane == 0) {
        flags[0] = (mb == ~0ULL) ? 1 : 0;
        flags[1] = (mz == ~0ULL) ? 1 : 0;
    }
}

// ---------------- Kernel A: CPE depthwise conv3 + residual, h -> ws ---------
template <typename XT>
__global__ void cpe_kernel(const int* __restrict__ flags,
                           const XT* __restrict__ x,
                           const XT* __restrict__ cw,
                           const XT* __restrict__ cb,
                           XT* __restrict__ h) {
    if ((flags[0] != 0) != (sizeof(XT) == 2)) return;
    int t = blockIdx.x * 256 + threadIdx.x;      // one thread per 4 channels
    int i  = t >> 4;
    int cg = (t & 15) << 2;
#pragma unroll
    for (int j = 0; j < 4; ++j) {
        int c = cg + j;
        float w0 = ldv(cw, c*3+0), w1 = ldv(cw, c*3+1), w2 = ldv(cw, c*3+2);
        float b  = ldv(cb, c);
        float xc = ldv(x, (long)i * C_CH + c);
        float xl = (i > 0)           ? ldv(x, (long)(i-1) * C_CH + c) : 0.f;
        float xr = (i < N_NODES - 1) ? ldv(x, (long)(i+1) * C_CH + c) : 0.f;
        float r = xc + b;
        r = fmaf(xl, w0, r);
        r = fmaf(xc, w1, r);
        r = fmaf(xr, w2, r);
        stv(h, (long)i * C_CH + c, r);
    }
}

// ---------------- Kernel B: gather + max-rel + [h,rel]@g_w + head + logsoftmax
template <typename XT, typename IT>
__global__ void graph_head_kernel(const int* __restrict__ flags,
                                  const XT* __restrict__ hws,
                                  const IT* __restrict__ nbr,
                                  const XT* __restrict__ gw,
                                  const XT* __restrict__ gb,
                                  const XT* __restrict__ ow,
                                  const XT* __restrict__ ob,
                                  XT* __restrict__ out) {
    if ((flags[0] != 0) != (sizeof(XT) == 2)) return;
    if ((flags[1] != 0) != (sizeof(IT) == 8)) return;

    // g_w pair-interleaved: sW[c*128 + co*2 + 0] = g_w[c][co]   (h part)
    //                       sW[c*128 + co*2 + 1] = g_w[64+c][co] (rel part)
    __shared__ float sW[64 * 128];     // 32 KB
    __shared__ float sOW[2592];        // o_w [64][40] + zero pad (reads reach 2583)
    __shared__ float sGB[64];
    __shared__ float sOB[64];
    __shared__ float sF[4][2][128];    // per-wave: 2 nodes x (h,rel interleaved)
    __shared__ float sH2[4][2][64];

    for (int t = threadIdx.x; t < 4096; t += 256) {
        int c = t >> 6, co = t & 63;
        sW[c*128 + co*2 + 0] = ldv(gw, c*64 + co);
        sW[c*128 + co*2 + 1] = ldv(gw, (64 + c)*64 + co);
    }
    for (int t = threadIdx.x; t < 2560; t += 256) sOW[t] = ldv(ow, t);
    for (int t = threadIdx.x; t < 32;   t += 256) sOW[2560 + t] = 0.f;
    if (threadIdx.x < 64) {
        sGB[threadIdx.x] = ldv(gb, threadIdx.x);
        sOB[threadIdx.x] = (threadIdx.x < NCLS) ? ldv(ob, threadIdx.x) : 0.f;
    }
    __syncthreads();

    const int lane = threadIdx.x & 63;
    const int wave = threadIdx.x >> 6;
    const int ngroups = N_NODES >> 3;   // 8 nodes per block-iteration

    for (int g = blockIdx.x; g < ngroups; g += gridDim.x) {
        const int nb = g * 8 + wave * 2;

        float hi0 = ldv(hws, (long)nb * C_CH + lane);
        float hi1 = ldv(hws, (long)(nb + 1) * C_CH + lane);

        int idxv = 0;
        if (lane < 32) idxv = ldi(nbr, (long)(nb + (lane >> 4)) * K_NBR + (lane & 15));

        float mx0 = -1e30f, mx1 = -1e30f;
#pragma unroll
        for (int k = 0; k < 16; ++k) {
            int j0 = __shfl(idxv, k, 64);
            int j1 = __shfl(idxv, 16 + k, 64);
            mx0 = fmaxf(mx0, ldv(hws, (long)j0 * C_CH + lane));
            mx1 = fmaxf(mx1, ldv(hws, (long)j1 * C_CH + lane));
        }

        sF[wave][0][2*lane] = hi0; sF[wave][0][2*lane + 1] = mx0 - hi0;
        sF[wave][1][2*lane] = hi1; sF[wave][1][2*lane + 1] = mx1 - hi1;
        __syncthreads();

        float a0 = hi0 + sGB[lane];
        float a1 = hi1 + sGB[lane];
        const float2* wp = (const float2*)sW;
        const float2* f0 = (const float2*)&sF[wave][0][0];
        const float2* f1 = (const float2*)&sF[wave][1][0];
#pragma unroll 8
        for (int c = 0; c < 64; ++c) {
            float2 w = wp[c*64 + lane];
            float2 u = f0[c];
            float2 v = f1[c];
            a0 = fmaf(u.x, w.x, a0); a0 = fmaf(u.y, w.y, a0);
            a1 = fmaf(v.x, w.x, a1); a1 = fmaf(v.y, w.y, a1);
        }
        sH2[wave][0][lane] = a0;
        sH2[wave][1][lane] = a1;
        __syncthreads();

        float l0 = 0.f, l1 = 0.f;
#pragma unroll 8
        for (int c = 0; c < 64; ++c) {
            float wv = sOW[c*40 + lane];   // lane>=40 reads pad/next row; masked below
            l0 = fmaf(sH2[wave][0][c], wv, l0);
            l1 = fmaf(sH2[wave][1][c], wv, l1);
        }
        l0 += sOB[lane];
        l1 += sOB[lane];

        float v0 = (lane < NCLS) ? l0 : -1e30f;
        float v1 = (lane < NCLS) ? l1 : -1e30f;
        float m0 = v0, m1 = v1;
#pragma unroll
        for (int off = 32; off; off >>= 1) {
            m0 = fmaxf(m0, __shfl_xor(m0, off, 64));
            m1 = fmaxf(m1, __shfl_xor(m1, off, 64));
        }
        float e0 = (lane < NCLS) ? __expf(v0 - m0) : 0.f;
        float e1 = (lane < NCLS) ? __expf(v1 - m1) : 0.f;
        float s0 = e0, s1 = e1;
#pragma unroll
        for (int off = 32; off; off >>= 1) {
            s0 += __shfl_xor(s0, off, 64);
            s1 += __shfl_xor(s1, off, 64);
        }
        if (lane < NCLS) {
            stv(out, (long)nb * NCLS + lane,       v0 - m0 - __logf(s0));
            stv(out, (long)(nb + 1) * NCLS + lane, v1 - m1 - __logf(s1));
        }
    }
}

extern "C" void kernel_launch(void* const* d_in, const int* in_sizes, int n_in,
                              void* d_out, int out_size, void* d_ws, size_t ws_size,
                              hipStream_t stream) {
    int* flags = (int*)d_ws;
    char* wsb  = (char*)d_ws + 1024;

    // Sniff dtypes on-device (graph-capture safe; recomputed every call)
    sniff_kernel<<<1, 64, 0, stream>>>(d_in[0], d_in[1], flags);

    const int cpe_blocks = (N_NODES * 16) / 256;

    // ---- bf16 variant ----
    {
        const ushort_t* x  = (const ushort_t*)d_in[0];
        const ushort_t* cw = (const ushort_t*)d_in[2];
        const ushort_t* cb = (const ushort_t*)d_in[3];
        const ushort_t* gw = (const ushort_t*)d_in[4];
        const ushort_t* gb = (const ushort_t*)d_in[5];
        const ushort_t* ow = (const ushort_t*)d_in[6];
        const ushort_t* ob = (const ushort_t*)d_in[7];
        ushort_t* out = (ushort_t*)d_out;
        ushort_t* hws = (ushort_t*)wsb;
        cpe_kernel<ushort_t><<<cpe_blocks, 256, 0, stream>>>(flags, x, cw, cb, hws);
        graph_head_kernel<ushort_t, int><<<768, 256, 0, stream>>>(
            flags, hws, (const int*)d_in[1], gw, gb, ow, ob, out);
        graph_head_kernel<ushort_t, long long><<<768, 256, 0, stream>>>(
            flags, hws, (const long long*)d_in[1], gw, gb, ow, ob, out);
    }
    // ---- f32 variant ----
    {
        const float* x  = (const float*)d_in[0];
        const float* cw = (const float*)d_in[2];
        const float* cb = (const float*)d_in[3];
        const float* gw = (const float*)d_in[4];
        const float* gb = (const float*)d_in[5];
        const float* ow = (const float*)d_in[6];
        const float* ob = (const float*)d_in[7];
        float* out = (float*)d_out;
        float* hws = (float*)wsb;
        cpe_kernel<float><<<cpe_blocks, 256, 0, stream>>>(flags, x, cw, cb, hws);
        graph_head_kernel<float, int><<<768, 256, 0, stream>>>(
            flags, hws, (const int*)d_in[1], gw, gb, ow, ob, out);
        graph_head_kernel<float, long long><<<768, 256, 0, stream>>>(
            flags, hws, (const long long*)d_in[1], gw, gb, ow, ob, out);
    }
}

// Round 7
// 372.312 us; speedup vs baseline: 1.3581x; 1.3581x over previous
//
#include <hip/hip_runtime.h>
#include <hip/hip_bf16.h>

#define N_NODES 262144
#define C_CH 64
#define K_NBR 16
#define NCLS 40

typedef unsigned short ushort_t;

__device__ __forceinline__ float bu2f(ushort_t u) {
    union { unsigned u32; float f; } v; v.u32 = ((unsigned)u) << 16; return v.f;
}
__device__ __forceinline__ ushort_t f2bu(float f) {
    union { float f; unsigned u; } v; v.f = f;
    unsigned r = v.u + 0x7FFFu + ((v.u >> 16) & 1u);
    return (ushort_t)(r >> 16);
}
__device__ __forceinline__ float lo16(unsigned u) {
    union { unsigned u32; float f; } v; v.u32 = u << 16; return v.f;
}
__device__ __forceinline__ float hi16(unsigned u) {
    union { unsigned u32; float f; } v; v.u32 = u & 0xffff0000u; return v.f;
}
__device__ __forceinline__ int ldi(const int* p, long i)       { return p[i]; }
__device__ __forceinline__ int ldi(const long long* p, long i) { return (int)p[i]; }

// ---------------- Sniffer: flags[1] = 1 if nbr is int64 ----------------------
__global__ void sniff_kernel(const void* __restrict__ nbr, int* __restrict__ flags) {
    int lane = threadIdx.x;                 // 64 threads
    const int* ni = (const int*)nbr;
    bool zodd = (ni[2 * lane + 1] == 0);    // int64 high words all zero
    unsigned long long mz = __ballot(zodd);
    if (lane == 0) flags[1] = (mz == ~0ULL) ? 1 : 0;
}

// ---------------- Kernel A: CPE depthwise conv3 + residual ------------------
// x, weights are FLOAT32 (proven by round-2/6 evidence). h stored as bf16 in ws
// (halves gather traffic; table fits aggregate L2). One thread = one channel x
// 4 consecutive nodes: 6 coalesced f32 loads + 4 coalesced bf16 stores.
__global__ void cpe_kernel(const float* __restrict__ x,
                           const float* __restrict__ cw,
                           const float* __restrict__ cb,
                           ushort_t* __restrict__ h) {
    int t  = blockIdx.x * 256 + threadIdx.x;   // [0, N/4 * 64)
    int ig = t >> 6;                           // node group
    int c  = t & 63;                           // channel (= lane)
    int i0 = ig << 2;                          // first node of group
    float w0 = cw[c * 3 + 0];
    float w1 = cw[c * 3 + 1];
    float w2 = cw[c * 3 + 2];
    float b  = cb[c];
    float v[6];
#pragma unroll
    for (int r = 0; r < 6; ++r) {
        int i = i0 - 1 + r;
        v[r] = (i >= 0 && i < N_NODES) ? x[(size_t)i * C_CH + c] : 0.f;
    }
#pragma unroll
    for (int j = 0; j < 4; ++j) {
        float r = v[j + 1] + b;
        r = fmaf(v[j],     w0, r);
        r = fmaf(v[j + 1], w1, r);
        r = fmaf(v[j + 2], w2, r);
        h[(size_t)(i0 + j) * C_CH + c] = f2bu(r);
    }
}

// ---------------- Kernel B: gather + max-rel + proj + head + logsoftmax -----
// 4 waves/block, 4 nodes per wave-iteration, full __syncthreads ordering.
// h gathered as bf16; all accumulation f32; weights in LDS as packed bf16
// (sW 16 KB + sOW 5 KB + scratch ~12.5 KB -> ~34 KB -> 4 blocks/CU).
template <typename IT>
__global__ void graph_head_kernel(const int* __restrict__ flags,
                                  const ushort_t* __restrict__ hws,
                                  const IT* __restrict__ nbr,
                                  const float* __restrict__ gw,
                                  const float* __restrict__ gb,
                                  const float* __restrict__ ow,
                                  const float* __restrict__ ob,
                                  float* __restrict__ out) {
    if ((flags[1] != 0) != (sizeof(IT) == 8)) return;

    // sW  [c2=0..31][co=0..63][4]: (W1[2c2][co], W2[2c2][co], W1[2c2+1][co], W2[2c2+1][co])
    // sOW [c4=0..15][co=0..39][4]: (O[4c4+0..3][co])
    __shared__ __align__(16) ushort_t sW[32 * 64 * 4];   // 16 KB
    __shared__ __align__(16) ushort_t sOW[16 * 40 * 4];  // 5 KB
    __shared__ float sGB[64], sOB[64];
    __shared__ __align__(16) float sF[4][4][128];        // 8 KB  (h,rel interleaved)
    __shared__ __align__(16) float sH2[4][4][64];        // 4 KB

    for (int t = threadIdx.x; t < 4096; t += 256) {
        int c = t >> 6, co = t & 63;
        int base = ((c >> 1) * 64 + co) * 4 + (c & 1) * 2;
        sW[base + 0] = f2bu(gw[c * 64 + co]);          // h-part W1[c][co]
        sW[base + 1] = f2bu(gw[(64 + c) * 64 + co]);   // rel-part W2[c][co]
    }
    for (int t = threadIdx.x; t < 2560; t += 256) {
        int c = t / 40, co = t - c * 40;
        sOW[((c >> 2) * 40 + co) * 4 + (c & 3)] = f2bu(ow[c * 40 + co]);
    }
    if (threadIdx.x < 64) {
        sGB[threadIdx.x] = gb[threadIdx.x];
        sOB[threadIdx.x] = (threadIdx.x < NCLS) ? ob[threadIdx.x] : 0.f;
    }
    __syncthreads();

    const int lane = threadIdx.x & 63;
    const int wave = threadIdx.x >> 6;
    const int co2  = (lane < NCLS) ? lane : lane - NCLS;  // head-col alias
    float* sFw  = &sF[wave][0][0];
    float* sH2w = &sH2[wave][0][0];
    const float gbv = sGB[lane];
    const float obv = sOB[lane];

    // grid 1024, groups 16384 -> exactly 16 uniform iterations per block
    for (int g = blockIdx.x; g < (N_NODES >> 4); g += gridDim.x) {
        const int nb = g * 16 + wave * 4;

        float hi[4], mx[4];
#pragma unroll
        for (int t = 0; t < 4; ++t) {
            hi[t] = bu2f(hws[(size_t)(nb + t) * C_CH + lane]);
            mx[t] = -1e30f;
        }
        int idxv = ldi(nbr, (long)nb * K_NBR + lane);   // 4 rows x 16 nbrs
#pragma unroll
        for (int t = 0; t < 4; ++t) {
#pragma unroll
            for (int k = 0; k < 16; ++k) {
                int j = __shfl(idxv, t * 16 + k, 64);
                mx[t] = fmaxf(mx[t], bu2f(hws[((size_t)(unsigned)j << 6) + lane]));
            }
        }
#pragma unroll
        for (int t = 0; t < 4; ++t) {
            sFw[t * 128 + 2 * lane]     = hi[t];
            sFw[t * 128 + 2 * lane + 1] = mx[t] - hi[t];
        }
        __syncthreads();

        float a[4];
#pragma unroll
        for (int t = 0; t < 4; ++t) a[t] = hi[t] + gbv;
        const uint2* wp = (const uint2*)sW;
        const float4* fp0 = (const float4*)(sFw);
        const float4* fp1 = (const float4*)(sFw + 128);
        const float4* fp2 = (const float4*)(sFw + 256);
        const float4* fp3 = (const float4*)(sFw + 384);
#pragma unroll 8
        for (int c2 = 0; c2 < 32; ++c2) {
            uint2 wu = wp[c2 * 64 + lane];           // dense 8B/lane, conflict-free
            float whe = lo16(wu.x), wre = hi16(wu.x);
            float who = lo16(wu.y), wro = hi16(wu.y);
            float4 u0 = fp0[c2], u1 = fp1[c2], u2 = fp2[c2], u3 = fp3[c2];
            a[0] = fmaf(u0.x, whe, a[0]); a[0] = fmaf(u0.y, wre, a[0]);
            a[0] = fmaf(u0.z, who, a[0]); a[0] = fmaf(u0.w, wro, a[0]);
            a[1] = fmaf(u1.x, whe, a[1]); a[1] = fmaf(u1.y, wre, a[1]);
            a[1] = fmaf(u1.z, who, a[1]); a[1] = fmaf(u1.w, wro, a[1]);
            a[2] = fmaf(u2.x, whe, a[2]); a[2] = fmaf(u2.y, wre, a[2]);
            a[2] = fmaf(u2.z, who, a[2]); a[2] = fmaf(u2.w, wro, a[2]);
            a[3] = fmaf(u3.x, whe, a[3]); a[3] = fmaf(u3.y, wre, a[3]);
            a[3] = fmaf(u3.z, who, a[3]); a[3] = fmaf(u3.w, wro, a[3]);
        }
#pragma unroll
        for (int t = 0; t < 4; ++t) sH2w[t * 64 + lane] = a[t];
        __syncthreads();

        float l[4] = {0.f, 0.f, 0.f, 0.f};
        const uint2* owp = (const uint2*)sOW;
        const float4* hp0 = (const float4*)(sH2w);
        const float4* hp1 = (const float4*)(sH2w + 64);
        const float4* hp2 = (const float4*)(sH2w + 128);
        const float4* hp3 = (const float4*)(sH2w + 192);
#pragma unroll 8
        for (int c4 = 0; c4 < 16; ++c4) {
            uint2 wu = owp[c4 * 40 + co2];
            float w0 = lo16(wu.x), w1 = hi16(wu.x);
            float w2 = lo16(wu.y), w3 = hi16(wu.y);
            float4 u0 = hp0[c4], u1 = hp1[c4], u2 = hp2[c4], u3 = hp3[c4];
            l[0] = fmaf(u0.x, w0, l[0]); l[0] = fmaf(u0.y, w1, l[0]);
            l[0] = fmaf(u0.z, w2, l[0]); l[0] = fmaf(u0.w, w3, l[0]);
            l[1] = fmaf(u1.x, w0, l[1]); l[1] = fmaf(u1.y, w1, l[1]);
            l[1] = fmaf(u1.z, w2, l[1]); l[1] = fmaf(u1.w, w3, l[1]);
            l[2] = fmaf(u2.x, w0, l[2]); l[2] = fmaf(u2.y, w1, l[2]);
            l[2] = fmaf(u2.z, w2, l[2]); l[2] = fmaf(u2.w, w3, l[2]);
            l[3] = fmaf(u3.x, w0, l[3]); l[3] = fmaf(u3.y, w1, l[3]);
            l[3] = fmaf(u3.z, w2, l[3]); l[3] = fmaf(u3.w, w3, l[3]);
        }
#pragma unroll
        for (int t = 0; t < 4; ++t) {
            float v = (lane < NCLS) ? (l[t] + obv) : -1e30f;
            float m = v;
#pragma unroll
            for (int off = 32; off; off >>= 1) m = fmaxf(m, __shfl_xor(m, off, 64));
            float e = (lane < NCLS) ? __expf(v - m) : 0.f;
            float s = e;
#pragma unroll
            for (int off = 32; off; off >>= 1) s += __shfl_xor(s, off, 64);
            if (lane < NCLS) out[(size_t)(nb + t) * NCLS + lane] = v - m - __logf(s);
        }
    }
}

extern "C" void kernel_launch(void* const* d_in, const int* in_sizes, int n_in,
                              void* d_out, int out_size, void* d_ws, size_t ws_size,
                              hipStream_t stream) {
    const float* x  = (const float*)d_in[0];
    const float* cw = (const float*)d_in[2];
    const float* cb = (const float*)d_in[3];
    const float* gw = (const float*)d_in[4];
    const float* gb = (const float*)d_in[5];
    const float* ow = (const float*)d_in[6];
    const float* ob = (const float*)d_in[7];
    float* out = (float*)d_out;

    int* flags = (int*)d_ws;
    ushort_t* hws = (ushort_t*)((char*)d_ws + 1024);   // N*64 bf16 = 32 MB

    sniff_kernel<<<1, 64, 0, stream>>>(d_in[1], flags);
    // CPE: N/4 node-groups x 64 channels
    cpe_kernel<<<(N_NODES / 4 * 64) / 256, 256, 0, stream>>>(x, cw, cb, hws);
    // 1024 persistent blocks (4 blocks/CU by LDS), 16 uniform iterations each
    graph_head_kernel<int><<<1024, 256, 0, stream>>>(
        flags, hws, (const int*)d_in[1], gw, gb, ow, ob, out);
    graph_head_kernel<long long><<<1024, 256, 0, stream>>>(
        flags, hws, (const long long*)d_in[1], gw, gb, ow, ob, out);
}